// Round 17
// baseline (3342.223 us; speedup 1.0000x reference)
//
#include <hip/hip_runtime.h>

// R17: R16 (5.4us/step) + two measured-cost fixes:
//  (1) per-slice distributed wait: thread tid's 16 h-loads all sit in column
//      (tid&127)*16 mod 2048 -> exactly ONE producer p=(tid&127)>>1. Each
//      thread polls only flag p then loads (wait overlaps stage; one barrier
//      joins -> block still transitively waits all 64 flags before its
//      F-write, so R16's ordering argument is unchanged). A-phase deleted.
//  (2) hls XOR-swizzle (T2): stride 2048 + col^((row&7)<<4) on write & read
//      -> C-phase ds_read_b128 2-way (free); SQ_LDS_BANK_CONFLICT was 16.8M.

typedef unsigned short u16;
typedef unsigned int u32;
typedef __attribute__((ext_vector_type(8))) short bf16x8;
typedef __attribute__((ext_vector_type(4))) float f32x4;
typedef __attribute__((ext_vector_type(4))) u32 u32x4;

#define NBLK 64
#define SEQ 512
#define BATCH 64
#define HID 1024
#define KDIM 2048
#define NGATES 4096
#define GB_STRIDE 68
#define XS_STRIDE 1032
#define SMEM_PP (64 * XS_STRIDE * 2)
#define FLAG_STRIDE 64
#define H_LDS_BYTES (64 * 2048)        // 131072, swizzled not padded
#define GB_BYTES (64 * GB_STRIDE * 4)  // 17408
#define HROW_BYTES (64 * 16 * 2)       // 2048
#define SMEM_SEQ (H_LDS_BYTES + GB_BYTES + HROW_BYTES)   // 150528
#define RS (64 * GB_STRIDE)            // one partial buffer, in floats

__device__ __forceinline__ u16 f2bf(float f) {
  u32 u = __builtin_bit_cast(u32, f);
  u += 0x7FFFu + ((u >> 16) & 1u);   // RNE
  return (u16)(u >> 16);
}
__device__ __forceinline__ float bf2f(u32 v) {
  return __builtin_bit_cast(float, v << 16);
}

__device__ __forceinline__ void llc_store_u16(u16* p, u16 v) {
  asm volatile("global_store_short %0, %1, off sc0 sc1" :: "v"(p), "v"((u32)v) : "memory");
}
__device__ __forceinline__ void llc_store_u32(u32* p, u32 v) {
  asm volatile("global_store_dword %0, %1, off sc0 sc1" :: "v"(p), "v"(v) : "memory");
}
__device__ __forceinline__ u32 llc_load_u32(const u32* p) {
  u32 r;
  asm volatile("global_load_dword %0, %1, off sc0 sc1\n\ts_waitcnt vmcnt(0)"
               : "=v"(r) : "v"(p) : "memory");
  return r;
}
__device__ __forceinline__ void llc_load_x4(u32x4& d, const void* p) {
  asm volatile("global_load_dwordx4 %0, %1, off sc0 sc1"
               : "=&v"(d) : "v"(p) : "memory");
}
__device__ __forceinline__ void llc_store_x4(void* p, u32x4 v) {
  asm volatile("global_store_dwordx4 %0, %1, off sc0 sc1" :: "v"(p), "v"(v) : "memory");
}

// ---------- prep_w ----------
__global__ void prep_w(const float* __restrict__ W, u16* __restrict__ Wt,
                       u32* __restrict__ bar) {
  __shared__ float tile[64][65];
  const int kb = blockIdx.x * 64;
  const int nb = blockIdx.y * 64;
  const int tx = threadIdx.x & 63;
  const int ty = threadIdx.x >> 6;
  for (int r = ty; r < 64; r += 4)
    tile[r][tx] = W[(size_t)(kb + r) * NGATES + nb + tx];
  __syncthreads();
  for (int r = ty; r < 64; r += 4)
    Wt[(size_t)(nb + r) * KDIM + kb + tx] = f2bf(tile[tx][r]);
  if (blockIdx.x == 0 && blockIdx.y == 0)
    for (int i = threadIdx.x; i < NBLK * FLAG_STRIDE; i += 256)
      bar[i] = 0;
}

// ---------- prep_x ----------
__global__ void prep_x(const float* __restrict__ x, u16* __restrict__ xb) {
  const size_t n4 = (size_t)SEQ * BATCH * HID / 4;
  size_t i = (size_t)blockIdx.x * blockDim.x + threadIdx.x;
  const size_t stride = (size_t)gridDim.x * blockDim.x;
  for (; i < n4; i += stride) {
    const float4 v = *(const float4*)(x + i * 4);
    u32 lo = (u32)f2bf(v.x) | ((u32)f2bf(v.y) << 16);
    u32 hi = (u32)f2bf(v.z) | ((u32)f2bf(v.w) << 16);
    *(uint2*)(xb + i * 4) = make_uint2(lo, hi);
  }
}

// ---------- prepass_gx ----------
__global__ __launch_bounds__(512) void prepass_gx(
    const u16* __restrict__ xb, const u16* __restrict__ Wt, u16* __restrict__ gxF)
{
  extern __shared__ u16 xs[];
  const int tid = threadIdx.x;
  const int lane = tid & 63;
  const int wv = tid >> 6;
  const int col16 = lane & 15;
  const int kg = lane >> 4;
  const int t0 = blockIdx.x * 2;

  for (int tp = 0; tp < 2; ++tp) {
    const int t = t0 + tp;
    if (tp) __syncthreads();
    const u16* xsrc = xb + (size_t)t * (BATCH * HID);
    #pragma unroll
    for (int it = 0; it < 16; ++it) {
      const int flat = it * 512 + tid;
      const int row = flat >> 7, k0 = (flat & 127) * 8;
      *(bf16x8*)(xs + row * XS_STRIDE + k0) = *(const bf16x8*)(xsrc + row * HID + k0);
    }
    __syncthreads();
    for (int nt = 0; nt < 32; ++nt) {
      const int col = wv * 512 + nt * 16 + col16;
      const u16* bp = Wt + (size_t)col * KDIM + HID + kg * 8;
      f32x4 acc[4];
      #pragma unroll
      for (int mt = 0; mt < 4; ++mt) acc[mt] = (f32x4){0.f, 0.f, 0.f, 0.f};
      #pragma unroll 4
      for (int kt = 0; kt < 32; ++kt) {
        const bf16x8 bw = *(const bf16x8*)(bp + kt * 32);
        #pragma unroll
        for (int mt = 0; mt < 4; ++mt) {
          const bf16x8 av = *(const bf16x8*)(xs + (mt * 16 + col16) * XS_STRIDE
                                                + kt * 32 + kg * 8);
          acc[mt] = __builtin_amdgcn_mfma_f32_16x16x32_bf16(av, bw, acc[mt], 0, 0, 0);
        }
      }
      const int g = wv >> 1;
      const int bid16 = (wv & 1) * 32 + nt;
      #pragma unroll
      for (int mt = 0; mt < 4; ++mt) {
        u16* dst = gxF + ((((size_t)bid16 * SEQ + t) * 4 + g) * 16 + col16) * 64
                       + mt * 16 + kg * 4;
        const u32 lo = (u32)f2bf(acc[mt][0]) | ((u32)f2bf(acc[mt][1]) << 16);
        const u32 hi = (u32)f2bf(acc[mt][2]) | ((u32)f2bf(acc[mt][3]) << 16);
        *(uint2*)dst = make_uint2(lo, hi);
      }
    }
  }
}

// ---------- lstm_seq: per-slice wait + swizzled hls ----------
__global__ __launch_bounds__(512, 2) void lstm_seq(
    const float* __restrict__ bias, const float* __restrict__ h0,
    const float* __restrict__ c0, const u16* __restrict__ Wt,
    const u16* __restrict__ gxF, u16* __restrict__ hbuf,
    float* __restrict__ out, u32* __restrict__ bar)
{
  extern __shared__ char smem[];
  char* hls  = smem;                                  // swizzled h copy; reused as partials
  float* part = (float*)smem;                         // [3][64][GB_STRIDE]
  float* gb  = (float*)(smem + H_LDS_BYTES);
  u16* hrow  = (u16*)(smem + H_LDS_BYTES + GB_BYTES);

  const int tid = threadIdx.x;
  const int bid = blockIdx.x;
  const int lane = tid & 63;
  const int wave = tid >> 6;
  const int nh = wave & 1;
  const int kq = wave >> 1;
  const int col16 = lane & 15;
  const int kg = lane >> 4;

  bf16x8 wh[8][2];
  #pragma unroll
  for (int kt = 0; kt < 8; ++kt)
    #pragma unroll
    for (int nt = 0; nt < 2; ++nt) {
      const int g = nh * 2 + nt;
      wh[kt][nt] = *(const bf16x8*)(Wt + (size_t)(g * HID + bid * 16 + col16) * KDIM
                                       + kq * 256 + kt * 32 + kg * 8);
    }
  const float bv0 = bias[(nh * 2 + 0) * HID + bid * 16 + col16];
  const float bv1 = bias[(nh * 2 + 1) * HID + bid * 16 + col16];

  const int r0 = tid >> 4;
  const int colg = bid * 16 + (tid & 15);
  float cst0 = c0[colg], cst1 = cst0;
  {
    const u16 h0b = f2bf(h0[colg]);
    llc_store_u16(hbuf + (size_t)r0 * HID + colg, h0b);
    llc_store_u16(hbuf + (size_t)(r0 + 32) * HID + colg, h0b);
  }
  __syncthreads();   // vmcnt drained per wave -> h0 at MALL
  if (tid == 0) llc_store_u32(bar + bid * FLAG_STRIDE, 1u);

  // this thread's sole h producer (its 16 loads all sit in that 32B column)
  const int prod = (tid & 127) >> 1;
  u32* myflag = bar + prod * FLAG_STRIDE;

  uint2 gxr[8];
  auto gxload = [&](int t) {
    if (kq == 0) {
      const u16* sb = gxF + ((size_t)bid * SEQ + t) * 4096;
      #pragma unroll
      for (int mt = 0; mt < 4; ++mt)
        #pragma unroll
        for (int nt = 0; nt < 2; ++nt)
          gxr[mt * 2 + nt] = *(const uint2*)(sb + ((nh * 2 + nt) * 16 + col16) * 64
                                                + mt * 16 + kg * 4);
    }
  };
  gxload(0);

  f32x4 acc[4][2];

  for (int t = 0; t < SEQ; ++t) {
    const u32 gen = (u32)t + 1;

    // ---- A+B fused: wait own producer, then stage slice -> swizzled LDS ----
    for (;;) {
      if (llc_load_u32(myflag) >= gen) break;
      __builtin_amdgcn_s_sleep(2);
    }
    {
      const char* hsrc = (const char*)hbuf + (size_t)(t & 1) * 131072;
      u32x4 hst[16];
      #pragma unroll
      for (int j = 0; j < 16; ++j)
        llc_load_x4(hst[j], hsrc + (j * 512 + tid) * 16);
      asm volatile("s_waitcnt vmcnt(0)" ::: "memory");
      __builtin_amdgcn_sched_barrier(0);
      #pragma unroll
      for (int j = 0; j < 16; ++j) {
        const int f = (j * 512 + tid) * 16;
        const int row = f >> 11;
        const int col = (f & 2047) ^ ((row & 7) << 4);   // T2 swizzle
        *(u32x4*)(hls + row * 2048 + col) = hst[j];
      }
    }
    __syncthreads();   // joins all threads = all 64 flags seen + LDS complete

    // ---- C. MFMA: A-frags from swizzled LDS, B from regs ----
    #pragma unroll
    for (int mt = 0; mt < 4; ++mt) {
      acc[mt][0] = (f32x4){0.f, 0.f, 0.f, 0.f};
      acc[mt][1] = (f32x4){0.f, 0.f, 0.f, 0.f};
    }
    #pragma unroll
    for (int mt = 0; mt < 4; ++mt) {
      const int row = col16 + mt * 16;
      const char* rowbase = hls + row * 2048;
      const int xr = (row & 7) << 4;
      const int cbase = kq * 512 + kg * 16;
      #pragma unroll
      for (int kt = 0; kt < 8; ++kt) {
        const bf16x8 av = *(const bf16x8*)(rowbase + ((cbase + kt * 64) ^ xr));
        acc[mt][0] = __builtin_amdgcn_mfma_f32_16x16x32_bf16(av, wh[kt][0], acc[mt][0], 0, 0, 0);
        acc[mt][1] = __builtin_amdgcn_mfma_f32_16x16x32_bf16(av, wh[kt][1], acc[mt][1], 0, 0, 0);
      }
    }

    // ---- D. reduce, NO atomics: disjoint partial writes + ONE barrier ----
    if (kq == 0) {
      #pragma unroll
      for (int mt = 0; mt < 4; ++mt)
        #pragma unroll
        for (int nt = 0; nt < 2; ++nt) {
          const float bv = nt ? bv1 : bv0;
          const uint2 gv = gxr[mt * 2 + nt];
          const float gx0 = bf2f(gv.x & 0xffffu), gx1 = bf2f(gv.x >> 16);
          const float gx2 = bf2f(gv.y & 0xffffu), gx3 = bf2f(gv.y >> 16);
          float* gp = gb + (mt * 16 + kg * 4) * GB_STRIDE + (nh * 2 + nt) * 16 + col16;
          gp[0 * GB_STRIDE] = acc[mt][nt][0] + bv + gx0;
          gp[1 * GB_STRIDE] = acc[mt][nt][1] + bv + gx1;
          gp[2 * GB_STRIDE] = acc[mt][nt][2] + bv + gx2;
          gp[3 * GB_STRIDE] = acc[mt][nt][3] + bv + gx3;
        }
    } else {
      float* pp = part + (kq - 1) * RS;
      #pragma unroll
      for (int mt = 0; mt < 4; ++mt)
        #pragma unroll
        for (int nt = 0; nt < 2; ++nt) {
          float* gp = pp + (mt * 16 + kg * 4) * GB_STRIDE + (nh * 2 + nt) * 16 + col16;
          gp[0 * GB_STRIDE] = acc[mt][nt][0];
          gp[1 * GB_STRIDE] = acc[mt][nt][1];
          gp[2 * GB_STRIDE] = acc[mt][nt][2];
          gp[3 * GB_STRIDE] = acc[mt][nt][3];
        }
    }
    __syncthreads();

    // ---- E. nonlinearity (sums gb + 3 partials inline) ----
    const int cl = tid & 15;
    #pragma unroll
    for (int cc = 0; cc < 2; ++cc) {
      const int row = r0 + cc * 32;
      const int ob = row * GB_STRIDE + cl;
      const float vf = gb[ob] + part[ob] + part[RS + ob] + part[2 * RS + ob];
      const float vi = gb[ob + 16] + part[ob + 16] + part[RS + ob + 16] + part[2 * RS + ob + 16];
      const float vg = gb[ob + 32] + part[ob + 32] + part[RS + ob + 32] + part[2 * RS + ob + 32];
      const float vo = gb[ob + 48] + part[ob + 48] + part[RS + ob + 48] + part[2 * RS + ob + 48];
      const float ft = 1.f / (1.f + __expf(-vf));
      const float it = 1.f / (1.f + __expf(-vi));
      const float eg = __expf(2.f * vg);
      const float gt = 1.f - 2.f / (eg + 1.f);     // tanh
      const float ot = 1.f / (1.f + __expf(-vo));
      const float cold = cc ? cst1 : cst0;
      const float cn = ft * cold + it * gt;
      const float ec = __expf(2.f * cn);
      const float th = 1.f - 2.f / (ec + 1.f);     // tanh
      const float hn = ot * th;
      if (cc) cst1 = cn; else cst0 = cn;
      hrow[row * 16 + cl] = f2bf(hn);
      if (t == SEQ - 1) {
        out[(size_t)row * HID + colg] = hn;
        out[(size_t)BATCH * HID + (size_t)row * HID + colg] = cn;
      }
    }
    __syncthreads();

    // ---- F. emit h as 64 x 32B contiguous chunks + release ----
    if (tid < 128) {
      const int row = tid >> 1, half = tid & 1;
      const u32x4 v = *(const u32x4*)(hrow + row * 16 + half * 8);
      char* dst = (char*)hbuf + (size_t)((t + 1) & 1) * 131072
                + (size_t)row * 2048 + bid * 32 + half * 16;
      llc_store_x4(dst, v);
    }
    __syncthreads();   // per-wave vmcnt drain: h stores ACKed at MALL
    if (t < SEQ - 1) {
      if (tid == 0) llc_store_u32(bar + bid * FLAG_STRIDE, gen + 1);
      gxload(t + 1);
    }
  }
}

extern "C" void kernel_launch(void* const* d_in, const int* in_sizes, int n_in,
                              void* d_out, int out_size, void* d_ws, size_t ws_size,
                              hipStream_t stream) {
  const float* x    = (const float*)d_in[0];
  const float* W    = (const float*)d_in[1];
  const float* bias = (const float*)d_in[2];
  const float* h0   = (const float*)d_in[3];
  const float* c0   = (const float*)d_in[4];
  float* out = (float*)d_out;

  char* w = (char*)d_ws;
  u16* Wt   = (u16*)w;                                        // 16 MB
  u16* xbq  = (u16*)(w + ((size_t)16 << 20));                 // 64 MB
  u16* hbuf = (u16*)(w + ((size_t)80 << 20));                 // 256 KB
  u32* bar  = (u32*)(w + ((size_t)80 << 20) + (512 << 10));   // 16 KB flags
  u16* gxF  = (u16*)(w + ((size_t)81 << 20));                 // 256 MB
  const size_t need = ((size_t)81 << 20) + ((size_t)256 << 20);
  if (ws_size < need) return;

  (void)hipFuncSetAttribute((const void*)prepass_gx,
                            hipFuncAttributeMaxDynamicSharedMemorySize, SMEM_PP);
  (void)hipFuncSetAttribute((const void*)lstm_seq,
                            hipFuncAttributeMaxDynamicSharedMemorySize, SMEM_SEQ);

  hipLaunchKernelGGL(prep_w, dim3(32, 64), dim3(256), 0, stream, W, Wt, bar);
  hipLaunchKernelGGL(prep_x, dim3(4096), dim3(256), 0, stream, x, xbq);
  hipLaunchKernelGGL(prepass_gx, dim3(256), dim3(512), SMEM_PP, stream, xbq, Wt, gxF);
  hipLaunchKernelGGL(lstm_seq, dim3(NBLK), dim3(512), SMEM_SEQ, stream,
                     bias, h0, c0, Wt, gxF, hbuf, out, bar);
}

// Round 18
// 3314.389 us; speedup vs baseline: 1.0084x; 1.0084x over previous
//
#include <hip/hip_runtime.h>

// R18: (1) lstm_seq = R16 layout (padded hls; R17's XOR swizzle RAISED
// conflicts 16.8M->50.3M, perf-null) + R17's per-producer fused wait (one
// barrier fewer). (2) prepass_gx restructured: 256 blocks = (col-strip bid&7,
// 16-t chunk bid>>3); round-robin XCD dispatch puts all 32 same-strip blocks
// on one XCD -> 1MB Wt strip L2-resident -> Wt LLC traffic 4GB -> ~8MB
// (prepass was 0.4ms at ~10TB/s LLC, traffic-bound).
// Step budget (R14/R15 attribution): poll~1 / stage~1.7 / mfma+reduce+nl~2.4.

typedef unsigned short u16;
typedef unsigned int u32;
typedef __attribute__((ext_vector_type(8))) short bf16x8;
typedef __attribute__((ext_vector_type(4))) float f32x4;
typedef __attribute__((ext_vector_type(4))) u32 u32x4;

#define NBLK 64
#define SEQ 512
#define BATCH 64
#define HID 1024
#define KDIM 2048
#define NGATES 4096
#define GB_STRIDE 68
#define XS_STRIDE 1032
#define SMEM_PP (64 * XS_STRIDE * 2)
#define FLAG_STRIDE 64
#define HPAD 32
#define HROW_STRIDE 2080
#define H_LDS_BYTES (64 * HROW_STRIDE)  // 133120
#define GB_BYTES (64 * GB_STRIDE * 4)   // 17408
#define HROW_BYTES (64 * 16 * 2)        // 2048
#define SMEM_SEQ (H_LDS_BYTES + GB_BYTES + HROW_BYTES)   // 152576
#define RS (64 * GB_STRIDE)

__device__ __forceinline__ u16 f2bf(float f) {
  u32 u = __builtin_bit_cast(u32, f);
  u += 0x7FFFu + ((u >> 16) & 1u);   // RNE
  return (u16)(u >> 16);
}
__device__ __forceinline__ float bf2f(u32 v) {
  return __builtin_bit_cast(float, v << 16);
}

__device__ __forceinline__ void llc_store_u16(u16* p, u16 v) {
  asm volatile("global_store_short %0, %1, off sc0 sc1" :: "v"(p), "v"((u32)v) : "memory");
}
__device__ __forceinline__ void llc_store_u32(u32* p, u32 v) {
  asm volatile("global_store_dword %0, %1, off sc0 sc1" :: "v"(p), "v"(v) : "memory");
}
__device__ __forceinline__ u32 llc_load_u32(const u32* p) {
  u32 r;
  asm volatile("global_load_dword %0, %1, off sc0 sc1\n\ts_waitcnt vmcnt(0)"
               : "=v"(r) : "v"(p) : "memory");
  return r;
}
__device__ __forceinline__ void llc_load_x4(u32x4& d, const void* p) {
  asm volatile("global_load_dwordx4 %0, %1, off sc0 sc1"
               : "=&v"(d) : "v"(p) : "memory");
}
__device__ __forceinline__ void llc_store_x4(void* p, u32x4 v) {
  asm volatile("global_store_dwordx4 %0, %1, off sc0 sc1" :: "v"(p), "v"(v) : "memory");
}

// ---------- prep_w ----------
__global__ void prep_w(const float* __restrict__ W, u16* __restrict__ Wt,
                       u32* __restrict__ bar) {
  __shared__ float tile[64][65];
  const int kb = blockIdx.x * 64;
  const int nb = blockIdx.y * 64;
  const int tx = threadIdx.x & 63;
  const int ty = threadIdx.x >> 6;
  for (int r = ty; r < 64; r += 4)
    tile[r][tx] = W[(size_t)(kb + r) * NGATES + nb + tx];
  __syncthreads();
  for (int r = ty; r < 64; r += 4)
    Wt[(size_t)(nb + r) * KDIM + kb + tx] = f2bf(tile[tx][r]);
  if (blockIdx.x == 0 && blockIdx.y == 0)
    for (int i = threadIdx.x; i < NBLK * FLAG_STRIDE; i += 256)
      bar[i] = 0;
}

// ---------- prep_x ----------
__global__ void prep_x(const float* __restrict__ x, u16* __restrict__ xb) {
  const size_t n4 = (size_t)SEQ * BATCH * HID / 4;
  size_t i = (size_t)blockIdx.x * blockDim.x + threadIdx.x;
  const size_t stride = (size_t)gridDim.x * blockDim.x;
  for (; i < n4; i += stride) {
    const float4 v = *(const float4*)(x + i * 4);
    u32 lo = (u32)f2bf(v.x) | ((u32)f2bf(v.y) << 16);
    u32 hi = (u32)f2bf(v.z) | ((u32)f2bf(v.w) << 16);
    *(uint2*)(xb + i * 4) = make_uint2(lo, hi);
  }
}

// ---------- prepass_gx: strip-per-XCD, 16 timesteps per block ----------
// block = (strip = bid&7 -> 512 gate cols, tchunk = bid>>3 -> 16 t). With
// round-robin XCD dispatch, all 32 same-strip blocks share one XCD's L2 ->
// the 1MB Wt strip is read from LLC once per XCD, then L2-hit for 16x32 t.
__global__ __launch_bounds__(512) void prepass_gx(
    const u16* __restrict__ xb, const u16* __restrict__ Wt, u16* __restrict__ gxF)
{
  extern __shared__ u16 xs[];     // [64][XS_STRIDE]
  const int tid = threadIdx.x;
  const int lane = tid & 63;
  const int wv = tid >> 6;
  const int col16 = lane & 15;
  const int kg = lane >> 4;
  const int strip = blockIdx.x & 7;
  const int tchunk = blockIdx.x >> 3;
  const int g = strip >> 1;

  for (int tp = 0; tp < 16; ++tp) {
    const int t = tchunk * 16 + tp;
    if (tp) __syncthreads();                 // protect xs overwrite
    const u16* xsrc = xb + (size_t)t * (BATCH * HID);
    #pragma unroll
    for (int it = 0; it < 16; ++it) {
      const int flat = it * 512 + tid;
      const int row = flat >> 7, k0 = (flat & 127) * 8;
      *(bf16x8*)(xs + row * XS_STRIDE + k0) = *(const bf16x8*)(xsrc + row * HID + k0);
    }
    __syncthreads();
    #pragma unroll
    for (int nt = 0; nt < 4; ++nt) {
      const int col = strip * 512 + wv * 64 + nt * 16 + col16;
      const u16* bp = Wt + (size_t)col * KDIM + HID + kg * 8;   // x-half of Wt row
      f32x4 acc[4];
      #pragma unroll
      for (int mt = 0; mt < 4; ++mt) acc[mt] = (f32x4){0.f, 0.f, 0.f, 0.f};
      #pragma unroll 4
      for (int kt = 0; kt < 32; ++kt) {
        const bf16x8 bw = *(const bf16x8*)(bp + kt * 32);
        #pragma unroll
        for (int mt = 0; mt < 4; ++mt) {
          const bf16x8 av = *(const bf16x8*)(xs + (mt * 16 + col16) * XS_STRIDE
                                                + kt * 32 + kg * 8);
          acc[mt] = __builtin_amdgcn_mfma_f32_16x16x32_bf16(av, bw, acc[mt], 0, 0, 0);
        }
      }
      const int bid16 = (strip & 1) * 32 + wv * 4 + nt;
      #pragma unroll
      for (int mt = 0; mt < 4; ++mt) {
        u16* dst = gxF + ((((size_t)bid16 * SEQ + t) * 4 + g) * 16 + col16) * 64
                       + mt * 16 + kg * 4;
        const u32 lo = (u32)f2bf(acc[mt][0]) | ((u32)f2bf(acc[mt][1]) << 16);
        const u32 hi = (u32)f2bf(acc[mt][2]) | ((u32)f2bf(acc[mt][3]) << 16);
        *(uint2*)dst = make_uint2(lo, hi);
      }
    }
  }
}

// ---------- lstm_seq: per-producer fused wait + padded hls (R16 layout) ----------
__global__ __launch_bounds__(512, 2) void lstm_seq(
    const float* __restrict__ bias, const float* __restrict__ h0,
    const float* __restrict__ c0, const u16* __restrict__ Wt,
    const u16* __restrict__ gxF, u16* __restrict__ hbuf,
    float* __restrict__ out, u32* __restrict__ bar)
{
  extern __shared__ char smem[];
  char* hls  = smem;                                  // padded h copy; reused as partials
  float* part = (float*)smem;                         // [3][64][GB_STRIDE]
  float* gb  = (float*)(smem + H_LDS_BYTES);
  u16* hrow  = (u16*)(smem + H_LDS_BYTES + GB_BYTES);

  const int tid = threadIdx.x;
  const int bid = blockIdx.x;
  const int lane = tid & 63;
  const int wave = tid >> 6;
  const int nh = wave & 1;
  const int kq = wave >> 1;
  const int col16 = lane & 15;
  const int kg = lane >> 4;

  bf16x8 wh[8][2];
  #pragma unroll
  for (int kt = 0; kt < 8; ++kt)
    #pragma unroll
    for (int nt = 0; nt < 2; ++nt) {
      const int g = nh * 2 + nt;
      wh[kt][nt] = *(const bf16x8*)(Wt + (size_t)(g * HID + bid * 16 + col16) * KDIM
                                       + kq * 256 + kt * 32 + kg * 8);
    }
  const float bv0 = bias[(nh * 2 + 0) * HID + bid * 16 + col16];
  const float bv1 = bias[(nh * 2 + 1) * HID + bid * 16 + col16];

  const int r0 = tid >> 4;
  const int colg = bid * 16 + (tid & 15);
  float cst0 = c0[colg], cst1 = cst0;
  {
    const u16 h0b = f2bf(h0[colg]);
    llc_store_u16(hbuf + (size_t)r0 * HID + colg, h0b);
    llc_store_u16(hbuf + (size_t)(r0 + 32) * HID + colg, h0b);
  }
  __syncthreads();
  if (tid == 0) llc_store_u32(bar + bid * FLAG_STRIDE, 1u);

  // each thread's 16 h-loads all come from ONE producer p = (tid&127)>>1
  u32* myflag = bar + (((tid & 127) >> 1) * FLAG_STRIDE);

  uint2 gxr[8];
  auto gxload = [&](int t) {
    if (kq == 0) {
      const u16* sb = gxF + ((size_t)bid * SEQ + t) * 4096;
      #pragma unroll
      for (int mt = 0; mt < 4; ++mt)
        #pragma unroll
        for (int nt = 0; nt < 2; ++nt)
          gxr[mt * 2 + nt] = *(const uint2*)(sb + ((nh * 2 + nt) * 16 + col16) * 64
                                                + mt * 16 + kg * 4);
    }
  };
  gxload(0);

  f32x4 acc[4][2];

  for (int t = 0; t < SEQ; ++t) {
    const u32 gen = (u32)t + 1;

    // ---- A+B fused: wait own producer then stage slice -> padded LDS ----
    for (;;) {
      if (llc_load_u32(myflag) >= gen) break;
      __builtin_amdgcn_s_sleep(2);
    }
    {
      const char* hsrc = (const char*)hbuf + (size_t)(t & 1) * 131072;
      u32x4 hst[16];
      #pragma unroll
      for (int j = 0; j < 16; ++j)
        llc_load_x4(hst[j], hsrc + (j * 512 + tid) * 16);
      asm volatile("s_waitcnt vmcnt(0)" ::: "memory");
      __builtin_amdgcn_sched_barrier(0);
      #pragma unroll
      for (int j = 0; j < 16; ++j) {
        const int f = (j * 512 + tid) * 16;
        *(u32x4*)(hls + f + (f >> 11) * HPAD) = hst[j];
      }
    }
    __syncthreads();   // joins all threads = all 64 producers seen + LDS done

    // ---- C. MFMA: A-frags from LDS, B from regs ----
    #pragma unroll
    for (int mt = 0; mt < 4; ++mt) {
      acc[mt][0] = (f32x4){0.f, 0.f, 0.f, 0.f};
      acc[mt][1] = (f32x4){0.f, 0.f, 0.f, 0.f};
    }
    #pragma unroll
    for (int mt = 0; mt < 4; ++mt) {
      const char* rbase = hls + (col16 + mt * 16) * HROW_STRIDE
                              + (kq * 256 + kg * 8) * 2;
      #pragma unroll
      for (int kt = 0; kt < 8; ++kt) {
        const bf16x8 av = *(const bf16x8*)(rbase + kt * 64);
        acc[mt][0] = __builtin_amdgcn_mfma_f32_16x16x32_bf16(av, wh[kt][0], acc[mt][0], 0, 0, 0);
        acc[mt][1] = __builtin_amdgcn_mfma_f32_16x16x32_bf16(av, wh[kt][1], acc[mt][1], 0, 0, 0);
      }
    }

    // ---- D. reduce: disjoint partials + ONE barrier ----
    if (kq == 0) {
      #pragma unroll
      for (int mt = 0; mt < 4; ++mt)
        #pragma unroll
        for (int nt = 0; nt < 2; ++nt) {
          const float bv = nt ? bv1 : bv0;
          const uint2 gv = gxr[mt * 2 + nt];
          const float gx0 = bf2f(gv.x & 0xffffu), gx1 = bf2f(gv.x >> 16);
          const float gx2 = bf2f(gv.y & 0xffffu), gx3 = bf2f(gv.y >> 16);
          float* gp = gb + (mt * 16 + kg * 4) * GB_STRIDE + (nh * 2 + nt) * 16 + col16;
          gp[0 * GB_STRIDE] = acc[mt][nt][0] + bv + gx0;
          gp[1 * GB_STRIDE] = acc[mt][nt][1] + bv + gx1;
          gp[2 * GB_STRIDE] = acc[mt][nt][2] + bv + gx2;
          gp[3 * GB_STRIDE] = acc[mt][nt][3] + bv + gx3;
        }
    } else {
      float* pp = part + (kq - 1) * RS;
      #pragma unroll
      for (int mt = 0; mt < 4; ++mt)
        #pragma unroll
        for (int nt = 0; nt < 2; ++nt) {
          float* gp = pp + (mt * 16 + kg * 4) * GB_STRIDE + (nh * 2 + nt) * 16 + col16;
          gp[0 * GB_STRIDE] = acc[mt][nt][0];
          gp[1 * GB_STRIDE] = acc[mt][nt][1];
          gp[2 * GB_STRIDE] = acc[mt][nt][2];
          gp[3 * GB_STRIDE] = acc[mt][nt][3];
        }
    }
    __syncthreads();

    // ---- E. nonlinearity (sums gb + 3 partials inline) ----
    const int cl = tid & 15;
    #pragma unroll
    for (int cc = 0; cc < 2; ++cc) {
      const int row = r0 + cc * 32;
      const int ob = row * GB_STRIDE + cl;
      const float vf = gb[ob] + part[ob] + part[RS + ob] + part[2 * RS + ob];
      const float vi = gb[ob + 16] + part[ob + 16] + part[RS + ob + 16] + part[2 * RS + ob + 16];
      const float vg = gb[ob + 32] + part[ob + 32] + part[RS + ob + 32] + part[2 * RS + ob + 32];
      const float vo = gb[ob + 48] + part[ob + 48] + part[RS + ob + 48] + part[2 * RS + ob + 48];
      const float ft = 1.f / (1.f + __expf(-vf));
      const float it = 1.f / (1.f + __expf(-vi));
      const float eg = __expf(2.f * vg);
      const float gt = 1.f - 2.f / (eg + 1.f);     // tanh
      const float ot = 1.f / (1.f + __expf(-vo));
      const float cold = cc ? cst1 : cst0;
      const float cn = ft * cold + it * gt;
      const float ec = __expf(2.f * cn);
      const float th = 1.f - 2.f / (ec + 1.f);     // tanh
      const float hn = ot * th;
      if (cc) cst1 = cn; else cst0 = cn;
      hrow[row * 16 + cl] = f2bf(hn);
      if (t == SEQ - 1) {
        out[(size_t)row * HID + colg] = hn;
        out[(size_t)BATCH * HID + (size_t)row * HID + colg] = cn;
      }
    }
    __syncthreads();

    // ---- F. emit h as 64 x 32B contiguous chunks + release ----
    if (tid < 128) {
      const int row = tid >> 1, half = tid & 1;
      const u32x4 v = *(const u32x4*)(hrow + row * 16 + half * 8);
      char* dst = (char*)hbuf + (size_t)((t + 1) & 1) * 131072
                + (size_t)row * 2048 + bid * 32 + half * 16;
      llc_store_x4(dst, v);
    }
    __syncthreads();   // per-wave vmcnt drain: h stores ACKed at MALL
    if (t < SEQ - 1) {
      if (tid == 0) llc_store_u32(bar + bid * FLAG_STRIDE, gen + 1);
      gxload(t + 1);
    }
  }
}

extern "C" void kernel_launch(void* const* d_in, const int* in_sizes, int n_in,
                              void* d_out, int out_size, void* d_ws, size_t ws_size,
                              hipStream_t stream) {
  const float* x    = (const float*)d_in[0];
  const float* W    = (const float*)d_in[1];
  const float* bias = (const float*)d_in[2];
  const float* h0   = (const float*)d_in[3];
  const float* c0   = (const float*)d_in[4];
  float* out = (float*)d_out;

  char* w = (char*)d_ws;
  u16* Wt   = (u16*)w;                                        // 16 MB
  u16* xbq  = (u16*)(w + ((size_t)16 << 20));                 // 64 MB
  u16* hbuf = (u16*)(w + ((size_t)80 << 20));                 // 256 KB
  u32* bar  = (u32*)(w + ((size_t)80 << 20) + (512 << 10));   // 16 KB flags
  u16* gxF  = (u16*)(w + ((size_t)81 << 20));                 // 256 MB
  const size_t need = ((size_t)81 << 20) + ((size_t)256 << 20);
  if (ws_size < need) return;

  (void)hipFuncSetAttribute((const void*)prepass_gx,
                            hipFuncAttributeMaxDynamicSharedMemorySize, SMEM_PP);
  (void)hipFuncSetAttribute((const void*)lstm_seq,
                            hipFuncAttributeMaxDynamicSharedMemorySize, SMEM_SEQ);

  hipLaunchKernelGGL(prep_w, dim3(32, 64), dim3(256), 0, stream, W, Wt, bar);
  hipLaunchKernelGGL(prep_x, dim3(4096), dim3(256), 0, stream, x, xbq);
  hipLaunchKernelGGL(prepass_gx, dim3(256), dim3(512), SMEM_PP, stream, xbq, Wt, gxF);
  hipLaunchKernelGGL(lstm_seq, dim3(NBLK), dim3(512), SMEM_SEQ, stream,
                     bias, h0, c0, Wt, gxF, hbuf, out, bar);
}